// Round 9
// baseline (660.157 us; speedup 1.0000x reference)
//
#include <hip/hip_runtime.h>

struct CgPtrs { const float* p[9]; };               // p[l1*3+l2]
struct Desc  { int s00, s01, s10, s11, Ereg, E; };

__host__ __device__ constexpr int DSL(int s){ return s<2?1:(s==2?3:5); }   // 2l+1 of slot
__host__ __device__ constexpr int PRE(int s){ return s==0?0:(s==1?1:(s==2?2:5)); } // prefix dim
__host__ __device__ constexpr int LSL(int s){ return s<2?0:(s==2?1:2); }   // l of slot
__host__ __device__ constexpr int OFT(int a,int b){ return PRE(a)*10 + DSL(a)*PRE(b); }
__host__ __device__ constexpr int RM(int r){ return r==0?0:r+1; }          // packed idx -> 10-dim idx

// ---- kernel 1: per-edge (rank,class) into ws; g2b floats into out tail ----
__global__ __launch_bounds__(256) void prep_kernel(
    const int* __restrict__ sel00, const int* __restrict__ sel01,
    const int* __restrict__ sel10, const int* __restrict__ sel11,
    Desc d, int* __restrict__ rank, float* __restrict__ og)
{
    int u = blockIdx.x*256 + threadIdx.x;
    if (u < d.s00){ int e=sel00[u]; rank[e]=(u<<2)|0; og[e]=(float)u; return; } u-=d.s00;
    if (u < d.s01){ int e=sel01[u]; rank[e]=(u<<2)|1; og[e]=(float)u; return; } u-=d.s01;
    if (u < d.s10){ int e=sel10[u]; rank[e]=(u<<2)|2; og[e]=(float)u; return; } u-=d.s10;
    if (u < d.s11){ int e=sel11[u]; rank[e]=(u<<2)|3; og[e]=(float)u; return; }
}

// acc[i][c0+j] += sum_k x[xo+k]*cgA[i][j][k] + y[yo+k]*cgB[j][i][k]
template<int S1, int S2>
__device__ __forceinline__ void chunk_fma(const float* x, const float* y,
                                          const CgPtrs& cg, float* acc)
{
    constexpr int d1=DSL(S1), d2=DSL(S2), K=d1*d2;
    constexpr int xo=OFT(S1,S2), yo=OFT(S2,S1);
    constexpr int c0=PRE(S2);
    const float* __restrict__ wA = cg.p[LSL(S1)*3+LSL(S2)];
    const float* __restrict__ wB = cg.p[LSL(S2)*3+LSL(S1)];
    float xc[K], yc[K];
    #pragma unroll
    for (int k=0;k<K;++k) xc[k]=x[xo+k];
    #pragma unroll
    for (int k=0;k<K;++k) yc[k]=y[yo+k];
    #pragma unroll
    for (int i=0;i<d1;++i)
        #pragma unroll
        for (int j=0;j<d2;++j){
            float a = acc[i*10 + c0 + j];
            #pragma unroll
            for (int k=0;k<K;++k) a = fmaf(xc[k], wA[(i*d2+j)*K+k], a);
            #pragma unroll
            for (int k=0;k<K;++k) a = fmaf(yc[k], wB[(j*d1+i)*K+k], a);
            acc[i*10 + c0 + j] = a;
        }
}

template<int S1>
__device__ __forceinline__ void band_run(const float* x, const float* y,
                                         const CgPtrs& cg, float* acc)
{
    chunk_fma<S1,0>(x,y,cg,acc);
    chunk_fma<S1,1>(x,y,cg,acc);
    chunk_fma<S1,2>(x,y,cg,acc);
    chunk_fma<S1,3>(x,y,cg,acc);
}

template<int S1>
__device__ __forceinline__ void band_store(float* dst, const float* acc)
{
    constexpr int n = DSL(S1)*10;
    #pragma unroll
    for (int u=0; u<n; ++u) dst[PRE(S1)*10 + u] = 0.5f*acc[u];
}

// coalesced per-class write-out from the LDS-assembled 10x10 mats
template<int C>
__device__ __forceinline__ void class_writeout(
    int tid, const float* __restrict__ xs, const int* __restrict__ pos,
    const int* __restrict__ basep, const int* __restrict__ cntp,
    float* __restrict__ o)
{
    constexpr int RC = (C==0)?16:((C==3)?100:40);
    const int n = cntp[C];
    const int b = basep[C];
    for (int idx = tid; idx < n*(RC/2); idx += 256){
        const int m  = idx/(RC/2);
        const int w  = 2*(idx - m*(RC/2));
        const float* src = xs + pos[C*64+m]*101;
        float v0, v1;
        if constexpr (C==3){ v0=src[w]; v1=src[w+1]; }
        else if constexpr (C==1){ int r=w/10, col=w-10*r; v0=src[RM(r)*10+col]; v1=src[RM(r)*10+col+1]; }
        else if constexpr (C==2){ int r=w>>2, col=w&3;    v0=src[r*10+RM(col)]; v1=src[r*10+RM(col+1)]; }
        else                    { int r=w>>2, col=w&3;    v0=src[RM(r)*10+RM(col)]; v1=src[RM(r)*10+RM(col+1)]; }
        *(float2*)(o + (size_t)(b+m)*RC + w) = make_float2(v0, v1);
    }
}

// ---- kernel 2: block = 64 consecutive edges; wave = row band; LDS-assembled output ----
__global__ __launch_bounds__(256,3) void ham_kernel(
    const float* __restrict__ fn, const float* __restrict__ fe,
    const int* __restrict__ rank,
    CgPtrs cg, Desc d, float* __restrict__ out)
{
    __shared__ float xs[64*101];
    __shared__ int   pos[256];
    __shared__ int   basep[4], cntp[4];

    float* o00 = out;
    float* o01 = o00 + (size_t)d.s00*16;
    float* o10 = o01 + (size_t)d.s01*40;
    float* o11 = o10 + (size_t)d.s10*40;

    const int e0  = blockIdx.x*64;
    const int tid = threadIdx.x;
    const int nE  = min(64, d.E - e0);

    // stage fe' rows, float4 global loads (self-tail: fn[e-Ereg] fused)
    for (int idx = tid; idx < nE*25; idx += 256){
        const int row = idx/25, q = idx - 25*row;
        const int e = e0 + row;
        float4 v = *(const float4*)(fe + (size_t)e*100 + 4*q);
        if (e >= d.Ereg){
            float4 w = *(const float4*)(fn + (size_t)(e - d.Ereg)*100 + 4*q);
            v.x += w.x; v.y += w.y; v.z += w.z; v.w += w.w;
        }
        float* dst = xs + row*101 + 4*q;
        dst[0]=v.x; dst[1]=v.y; dst[2]=v.z; dst[3]=v.w;
    }
    // wave 0: class metadata (pos/base/cnt via ballot)
    if (tid < 4) cntp[tid] = 0;
    if (tid < 64){
        const int e = e0 + tid;
        const bool valid = (tid < nE);
        const int pk = valid ? rank[e] : -1;
        const int c_me = valid ? (pk & 3) : -1;
        const unsigned long long b0 = __ballot(c_me==0), b1 = __ballot(c_me==1),
                                 b2 = __ballot(c_me==2), b3 = __ballot(c_me==3);
        if (valid){
            const unsigned long long mym = (c_me==0)?b0:(c_me==1)?b1:(c_me==2)?b2:b3;
            const int p = __popcll(mym & ((1ull<<tid)-1ull));
            pos[c_me*64 + p] = tid;
            if (p == 0){ basep[c_me] = pk >> 2; cntp[c_me] = __popcll(mym); }
        }
    }
    __syncthreads();

    // compute: wave = band (rotated); class-independent full band rows
    const int lane = tid & 63;
    const int band = ((tid>>6) + blockIdx.x) & 3;
    const int e = e0 + lane;
    float acc[50];                        // max band: d1=5 rows x 10
    #pragma unroll
    for (int i=0;i<50;++i) acc[i]=0.f;
    if (lane < nE){
        const float* x = xs + lane*101;
        const float* y = (e >= d.Ereg) ? x : xs + (lane^1)*101;  // inv(e)=e^1; self: y=x
        if      (band==0) band_run<0>(x,y,cg,acc);
        else if (band==1) band_run<1>(x,y,cg,acc);
        else if (band==2) band_run<2>(x,y,cg,acc);
        else              band_run<3>(x,y,cg,acc);
    }
    __syncthreads();                      // all reads of xs done
    if (lane < nE){
        float* dst = xs + lane*101;
        if      (band==0) band_store<0>(dst, acc);
        else if (band==1) band_store<1>(dst, acc);
        else if (band==2) band_store<2>(dst, acc);
        else              band_store<3>(dst, acc);
    }
    __syncthreads();                      // mats assembled

    class_writeout<0>(tid, xs, pos, basep, cntp, o00);
    class_writeout<1>(tid, xs, pos, basep, cntp, o01);
    class_writeout<2>(tid, xs, pos, basep, cntp, o10);
    class_writeout<3>(tid, xs, pos, basep, cntp, o11);
}

extern "C" void kernel_launch(void* const* d_in, const int* in_sizes, int n_in,
                              void* d_out, int out_size, void* d_ws, size_t ws_size,
                              hipStream_t stream)
{
    const float* fn  = (const float*)d_in[0];
    const float* fe  = (const float*)d_in[1];
    CgPtrs cg;
    for (int i = 0; i < 9; ++i) cg.p[i] = (const float*)d_in[6 + i];
    const int* sel00 = (const int*)d_in[15];
    const int* sel01 = (const int*)d_in[16];
    const int* sel10 = (const int*)d_in[17];
    const int* sel11 = (const int*)d_in[18];

    const int N = in_sizes[0] / 100;
    const int E = in_sizes[3] / 2;

    Desc d;
    d.s00 = in_sizes[15]; d.s01 = in_sizes[16]; d.s10 = in_sizes[17]; d.s11 = in_sizes[18];
    d.Ereg = E - N;
    d.E = E;

    float* out = (float*)d_out;
    float* og  = out + (size_t)d.s00*16 + (size_t)d.s01*40 + (size_t)d.s10*40 + (size_t)d.s11*100;
    int* rank = (int*)d_ws;              // E ints

    prep_kernel<<<(E + 255)/256, 256, 0, stream>>>(sel00, sel01, sel10, sel11, d, rank, og);
    ham_kernel <<<(E + 63)/64,   256, 0, stream>>>(fn, fe, rank, cg, d, out);
}

// Round 10
// 131.847 us; speedup vs baseline: 5.0070x; 5.0070x over previous
//
#include <hip/hip_runtime.h>

struct CgPtrs { const float* p[9]; };               // p[l1*3+l2]
struct Desc  { int r0,r1,r2,r3,r4,r5; int s00,s01,s10,s11,Ereg,E; };

__host__ __device__ constexpr int DSL(int s){ return s<2?1:(s==2?3:5); }   // 2l+1 of slot
__host__ __device__ constexpr int PRE(int s){ return s==0?0:(s==1?1:(s==2?2:5)); }
__host__ __device__ constexpr int LSL(int s){ return s<2?0:(s==2?1:2); }
__host__ __device__ constexpr int OFT(int a,int b){ return PRE(a)*10 + DSL(a)*PRE(b); }
__host__ __device__ constexpr int ROF(int T,int s){ return T ? PRE(s) : (s==0?0:1); }

// one (S1,S2) slot-pair contraction into the band accumulator (packed width W)
template<int S1,int S2,int T2>
__device__ __forceinline__ void chunk(const float* __restrict__ xr,
    const float* __restrict__ yr, const float* __restrict__ nr,
    bool slf, bool anyslf, const CgPtrs& cg, float* acc)
{
    constexpr int d1=DSL(S1), d2=DSL(S2), K=d1*d2;
    constexpr int xo=OFT(S1,S2), yo=OFT(S2,S1);
    constexpr int W = T2?10:4;
    constexpr int co = ROF(T2,S2);
    const float* __restrict__ wA = cg.p[LSL(S1)*3+LSL(S2)];   // cg_{l1,l2}[i][j][k]
    const float* __restrict__ wB = cg.p[LSL(S2)*3+LSL(S1)];   // cg_{l2,l1}[j][i][k]
    float xc[K], yc[K];
    #pragma unroll
    for (int k=0;k<K;++k) xc[k]=xr[xo+k];
    #pragma unroll
    for (int k=0;k<K;++k) yc[k]=yr[yo+k];
    if (anyslf){
        #pragma unroll
        for (int k=0;k<K;++k){ float nv=nr[xo+k]; xc[k] += slf ? nv : 0.f; }
        #pragma unroll
        for (int k=0;k<K;++k){ float nv=nr[yo+k]; yc[k] += slf ? nv : 0.f; }
    }
    #pragma unroll
    for (int i=0;i<d1;++i)
      #pragma unroll
      for (int j=0;j<d2;++j){
        float a = acc[i*W+co+j];
        #pragma unroll
        for (int k=0;k<K;++k) a = fmaf(xc[k], wA[(i*d2+j)*K+k], a);
        #pragma unroll
        for (int k=0;k<K;++k) a = fmaf(yc[k], wB[(j*d1+i)*K+k], a);
        acc[i*W+co+j] = a;
      }
}

// band S1 of a (T1,T2) matrix; optionally also write the transposed partner mat
template<int S1,int T1,int T2,bool TR>
__device__ __forceinline__ void band(const float* xr,const float* yr,const float* nr,
    bool slf,bool anyslf,const CgPtrs& cg, float* __restrict__ o1, float* __restrict__ o2)
{
    constexpr int d1 = DSL(S1);
    constexpr int W2 = T2?10:4;          // direct mat width
    constexpr int W1 = T1?10:4;          // partner mat width
    constexpr int RO = ROF(T1,S1);
    float acc[d1*W2];
    #pragma unroll
    for (int i=0;i<d1*W2;++i) acc[i]=0.f;
    if constexpr (T2){
        chunk<S1,0,1>(xr,yr,nr,slf,anyslf,cg,acc);
        chunk<S1,1,1>(xr,yr,nr,slf,anyslf,cg,acc);
        chunk<S1,2,1>(xr,yr,nr,slf,anyslf,cg,acc);
        chunk<S1,3,1>(xr,yr,nr,slf,anyslf,cg,acc);
    } else {
        chunk<S1,0,0>(xr,yr,nr,slf,anyslf,cg,acc);
        chunk<S1,2,0>(xr,yr,nr,slf,anyslf,cg,acc);
    }
    float* dst = o1 + RO*W2;
    #pragma unroll
    for (int u=0; u<d1*W2/2; ++u)
        *(float2*)(dst + 2*u) = make_float2(0.5f*acc[2*u], 0.5f*acc[2*u+1]);
    if constexpr (TR){
        #pragma unroll
        for (int j=0;j<W2;++j)
            #pragma unroll
            for (int i=0;i<d1;++i)
                o2[j*W1 + RO + i] = 0.5f*acc[i*W2+j];
    }
}

template<int T1,int T2,bool TR>
__device__ __forceinline__ void all_bands(const float* xr,const float* yr,const float* nr,
    bool slf,bool anyslf,const CgPtrs& cg, float* o1, float* o2)
{
    if constexpr (T1){
        band<0,T1,T2,TR>(xr,yr,nr,slf,anyslf,cg,o1,o2);
        band<1,T1,T2,TR>(xr,yr,nr,slf,anyslf,cg,o1,o2);
        band<2,T1,T2,TR>(xr,yr,nr,slf,anyslf,cg,o1,o2);
        band<3,T1,T2,TR>(xr,yr,nr,slf,anyslf,cg,o1,o2);
    } else {
        band<0,T1,T2,TR>(xr,yr,nr,slf,anyslf,cg,o1,o2);
        band<2,T1,T2,TR>(xr,yr,nr,slf,anyslf,cg,o1,o2);
    }
}

__global__ __launch_bounds__(256,2) void fused_kernel(
    const float* __restrict__ fn, const float* __restrict__ fe,
    const int* __restrict__ sel00, const int* __restrict__ sel01,
    const int* __restrict__ sel10, const int* __restrict__ sel11,
    CgPtrs cg, Desc d, float* __restrict__ out)
{
    float* o00 = out;
    float* o01 = o00 + (size_t)d.s00*16;
    float* o10 = o01 + (size_t)d.s01*40;
    float* o11 = o10 + (size_t)d.s10*40;
    float* og  = o11 + (size_t)d.s11*100;
    const int bid = blockIdx.x;
    const int tid = threadIdx.x;

    if (bid < d.r0) {                    // A: c3 regular pairs (2 mats/lane)
        const int m = bid*256 + tid;
        bool act = (2*m+1 < d.s11);
        const int e1 = act ? sel11[2*m] : 0;
        act = act && (e1 < d.Ereg);
        if (!act) return;
        const float* xr = fe + (size_t)e1*100;
        const float* yr = xr + 100;                  // e1 even; partner = e1+1
        float* o1 = o11 + (size_t)(2*m)*100;
        all_bands<1,1,true>(xr, yr, fe, false, false, cg, o1, o1+100);
        return;
    }
    if (bid < d.r1) {                    // C: c1 + c2 merged (out10[j] = out01[j]^T)
        const int u = (bid-d.r0)*256 + tid;
        if (u >= d.s01) return;
        const int e1 = sel01[u];
        const float* xr = fe + (size_t)e1*100;
        const float* yr = fe + (size_t)(e1^1)*100;   // inverse edge
        all_bands<0,1,true>(xr, yr, fe, false, false, cg,
                            o01 + (size_t)u*40, o10 + (size_t)u*40);
        return;
    }
    if (bid < d.r2) {                    // B: c3 self edges (tail ranks)
        const int j = d.s11 - 1 - ((bid-d.r1)*256 + tid);
        bool act = (j >= 0);
        const int e = act ? sel11[j] : 0;
        act = act && (e >= d.Ereg);
        if (!act) return;
        const float* xr = fe + (size_t)e*100;
        const float* nr = fn + (size_t)(e - d.Ereg)*100;
        float* o1 = o11 + (size_t)j*100;
        all_bands<1,1,false>(xr, xr, nr, true, true, cg, o1, o1);
        return;
    }
    if (bid < d.r3) {                    // D: c0 regular pairs
        const int m = (bid-d.r2)*256 + tid;
        bool act = (2*m+1 < d.s00);
        const int e1 = act ? sel00[2*m] : 0;
        act = act && (e1 < d.Ereg);
        if (!act) return;
        const float* xr = fe + (size_t)e1*100;
        float* o1 = o00 + (size_t)(2*m)*16;
        all_bands<0,0,true>(xr, xr+100, fe, false, false, cg, o1, o1+16);
        return;
    }
    if (bid < d.r4) {                    // E: c0 self edges (tail ranks)
        const int j = d.s00 - 1 - ((bid-d.r3)*256 + tid);
        bool act = (j >= 0);
        const int e = act ? sel00[j] : 0;
        act = act && (e >= d.Ereg);
        if (!act) return;
        const float* xr = fe + (size_t)e*100;
        const float* nr = fn + (size_t)(e - d.Ereg)*100;
        float* o1 = o00 + (size_t)j*16;
        all_bands<0,0,false>(xr, xr, nr, true, true, cg, o1, o1);
        return;
    }
    // F: g2b scatter (float-encoded ranks; counts < 2^24 so exact)
    {
        int u = (bid - d.r4)*256 + tid;
        if (u < d.s00) { og[sel00[u]] = (float)u; return; }  u -= d.s00;
        if (u < d.s01) { og[sel01[u]] = (float)u; return; }  u -= d.s01;
        if (u < d.s10) { og[sel10[u]] = (float)u; return; }  u -= d.s10;
        if (u < d.s11) { og[sel11[u]] = (float)u; return; }
    }
}

extern "C" void kernel_launch(void* const* d_in, const int* in_sizes, int n_in,
                              void* d_out, int out_size, void* d_ws, size_t ws_size,
                              hipStream_t stream)
{
    const float* fn  = (const float*)d_in[0];
    const float* fe  = (const float*)d_in[1];
    CgPtrs cg;
    for (int i = 0; i < 9; ++i) cg.p[i] = (const float*)d_in[6 + i];
    const int* sel00 = (const int*)d_in[15];
    const int* sel01 = (const int*)d_in[16];
    const int* sel10 = (const int*)d_in[17];
    const int* sel11 = (const int*)d_in[18];

    const int N = in_sizes[0] / 100;
    const int E = in_sizes[3] / 2;

    Desc d;
    d.s00 = in_sizes[15]; d.s01 = in_sizes[16]; d.s10 = in_sizes[17]; d.s11 = in_sizes[18];
    d.Ereg = E - N;
    d.E = E;
    const int tot = d.s00 + d.s01 + d.s10 + d.s11;

    const int m11 = d.s11 < N ? d.s11 : N;
    const int m00 = d.s00 < N ? d.s00 : N;
    const int nA = ((d.s11 + 1)/2 + 255) / 256;
    const int nC = (d.s01 + 255) / 256;
    const int nB = (m11 + 255) / 256;
    const int nD = ((d.s00 + 1)/2 + 255) / 256;
    const int nE_ = (m00 + 255) / 256;
    const int nF = (tot + 255) / 256;

    d.r0 = nA;
    d.r1 = d.r0 + nC;
    d.r2 = d.r1 + nB;
    d.r3 = d.r2 + nD;
    d.r4 = d.r3 + nE_;
    d.r5 = d.r4 + nF;

    if (d.r5 > 0)
        fused_kernel<<<d.r5, 256, 0, stream>>>(
            fn, fe, sel00, sel01, sel10, sel11, cg, d, (float*)d_out);
}